// Round 10
// baseline (50.608 us; speedup 1.0000x reference)
//
#include <hip/hip_runtime.h>

#define HALF 16
#define IMW  512
#define IMH  512
#define TW   64                // tile width
#define TH   32                // tile height
#define NTX  (IMW / TW)        // 8 tile columns
#define NTY  (IMH / TH)        // 16 tile rows
#define TPI  (NTX * NTY)       // 128 tiles per image
#define CAP  64                // landmark list capacity

typedef float f32x4 __attribute__((ext_vector_type(4)));

// PROBE ROUND (r6 kernel + ghost writes): discriminate "fixed ~10us window
// cost" vs "real 3.3 TB/s steady store rate". Each thread stores its 32 B
// output AND mirrors it into `ng` 64-MiB ghost regions of d_ws, bringing
// total writes to 256 MiB == the poison fill's size, and surfacing this
// dispatch in the top-5 counter table (FETCH_SIZE => RFO check).
__global__ __launch_bounds__(256)
void lm_probe_kernel(const float* __restrict__ landmarks,  // [B, L, 2]
                     float* __restrict__ out,              // [B, IMH*IMW]
                     float* __restrict__ ghost,            // d_ws regions
                     int L, int ng)
{
    __shared__ float2 slm[CAP];
    __shared__ int sn;

    const int t    = threadIdx.x;
    const int bx   = blockIdx.x;
    const int b    = bx >> 7;            // TPI == 128
    const int tile = bx & (TPI - 1);
    const int tx   = tile & (NTX - 1);
    const int ty   = tile >> 3;
    const int C    = tx * TW;
    const int R    = ty * TH;

    if (t == 0) sn = 0;
    __syncthreads();

    // Phase 1: gather this tile's landmarks into LDS.
    const float2* lmb = reinterpret_cast<const float2*>(landmarks) + (size_t)b * L;
    for (int j = t; j < L; j += 256) {
        float2 lm = lmb[j];
        float x0 = fminf(fmaxf(lm.x, (float)HALF), (float)(IMW - 1 - HALF));
        float x1 = fminf(fmaxf(lm.y, (float)HALF), (float)(IMH - 1 - HALF));
        int i0 = (int)x0;
        int i1 = (int)x1;
        bool hit = (unsigned)(i0 - (C - HALF)) < (unsigned)(TW + 2 * HALF)
                && (unsigned)(i1 - (R - HALF)) < (unsigned)(TH + 2 * HALF);
        if (hit) {
            int pos = atomicAdd(&sn, 1);
            if (pos < CAP) slm[pos] = make_float2(x0, x1);
        }
    }
    __syncthreads();
    const int n = min(sn, CAP);

    // Phase 2: 8 contiguous pixels per thread, one row.
    const int   py  = R + (t >> 3);
    const int   px0 = C + (t & 7) * 8;
    const float fpy = (float)py;

    float acc[8] = {0, 0, 0, 0, 0, 0, 0, 0};
    for (int j = 0; j < n; ++j) {
        float2 e = slm[j];
        int   i0   = (int)e.x;
        int   i1   = (int)e.y;
        float dy   = fpy - e.y;
        float dy2e = dy * dy + 1e-6f;
        bool  in1  = (unsigned)(py - i1 + HALF) <= (unsigned)(2 * HALF);
        #pragma unroll
        for (int c = 0; c < 8; ++c) {
            int   px  = px0 + c;
            float dx  = (float)px - e.x;
            bool  in0 = (unsigned)(px - i0 + HALF) <= (unsigned)(2 * HALF);
            float v = __builtin_amdgcn_rcpf(1.0f + __builtin_amdgcn_sqrtf(dx * dx + dy2e));
            acc[c] += (in0 && in1) ? v : 0.0f;
        }
    }

    // Phase 3: real output stores + ghost stores (identical pattern, d_ws).
    const size_t off = (size_t)b * (IMH * IMW) + (size_t)py * IMW + px0;
    f32x4 v0 = { acc[0], acc[1], acc[2], acc[3] };
    f32x4 v1 = { acc[4], acc[5], acc[6], acc[7] };
    reinterpret_cast<f32x4*>(out + off)[0] = v0;
    reinterpret_cast<f32x4*>(out + off)[1] = v1;
    const size_t region = (size_t)64 * IMH * IMW;   // 16.78M floats = 64 MiB
    for (int r = 0; r < ng; ++r) {
        float* g = ghost + (size_t)r * region + off;
        reinterpret_cast<f32x4*>(g)[0] = v0;
        reinterpret_cast<f32x4*>(g)[1] = v1;
    }
}

extern "C" void kernel_launch(void* const* d_in, const int* in_sizes, int n_in,
                              void* d_out, int out_size, void* d_ws, size_t ws_size,
                              hipStream_t stream)
{
    // d_in[0] = img (unused by the reference); d_in[1] = landmarks [B, L, 2] f32
    const float* landmarks = (const float*)d_in[1];
    float* out = (float*)d_out;

    const int B = out_size / (IMH * IMW);   // 64
    const int L = in_sizes[1] / (2 * B);    // 106

    // Ghost regions: as many 64-MiB mirrors as fit (target 3 -> 256 MiB total writes).
    const size_t region_bytes = (size_t)out_size * sizeof(float);   // 64 MiB
    int ng = (int)(ws_size / region_bytes);
    if (ng > 3) ng = 3;

    lm_probe_kernel<<<B * TPI, 256, 0, stream>>>(landmarks, out, (float*)d_ws, L, ng);
}

// Round 11
// 33.342 us; speedup vs baseline: 1.5178x; 1.5178x over previous
//
#include <hip/hip_runtime.h>

#define HALF 16
#define IMW  512
#define IMH  512
#define BH   16                // band height (rows per block)
#define NBND (IMH / BH)        // 32 bands per image
#define NSUB 16                // 32-px-wide column subtiles
#define CAP  25                // per-subtile list capacity (padded: 25*2 words
                               // => subtile stride 50 mod 32 banks spreads the
                               // 8 concurrent broadcast groups over banks)

typedef float f32x4 __attribute__((ext_vector_type(4)));

// Row-sweep kernel. Block = one 512x16 band (32 KB linear output), 4 waves.
// Phase 1: bin the image's landmarks into 16 col-subtile LDS lists
// (row window: i1 in [R-16, R+31]; col: a 33-px span covers exactly 2
// 32-px subtiles). Phase 2: wave w owns rows R+4w..R+4w+3 and sweeps them
// in address order; each wave-store instruction writes 1 KB CONTIGUOUS
// (64 lanes x f32x4), so every wave maintains an advancing linear store
// frontier (fill-like), with evals interleaved between stores instead of
// a global compute-phase/store-phase lockstep. 2048 blocks = 8/CU, all
// resident in one generation; 3.3 KB LDS; XCD-chunked swizzle keeps each
// XCD's frontiers inside one contiguous 8-MB region.
__global__ __launch_bounds__(256)
void lm_rowsweep_kernel(const float* __restrict__ landmarks,  // [B, L, 2]
                        float* __restrict__ out,              // [B, IMH*IMW]
                        int L)
{
    __shared__ float2 slist[NSUB][CAP];
    __shared__ int    scnt[NSUB];

    const int t  = threadIdx.x;
    // XCD-chunked bijective swizzle (grid 2048, 2048 % 8 == 0).
    const int bx = (blockIdx.x & 7) * 256 + (blockIdx.x >> 3);
    const int b    = bx >> 5;            // image
    const int band = bx & (NBND - 1);
    const int R    = band * BH;          // rows [R, R+16)

    if (t < NSUB) scnt[t] = 0;
    __syncthreads();

    // Phase 1: single pass over this image's landmarks (L=106 <= 256).
    const float2* lmb = reinterpret_cast<const float2*>(landmarks) + (size_t)b * L;
    for (int j = t; j < L; j += 256) {
        float2 lm = lmb[j];
        float x0 = fminf(fmaxf(lm.x, (float)HALF), (float)(IMW - 1 - HALF));
        float x1 = fminf(fmaxf(lm.y, (float)HALF), (float)(IMH - 1 - HALF));
        int i0 = (int)x0;                // coords >= 16, trunc == floor
        int i1 = (int)x1;
        // rows: patch [i1-16, i1+16] intersects [R, R+16) iff i1 in [R-16, R+31]
        if ((unsigned)(i1 - (R - HALF)) < (unsigned)(BH + 2 * HALF)) {
            int g0 = (i0 - HALF) >> 5;   // in [0,14]; span 33 covers exactly {g0, g0+1}
            int p0 = atomicAdd(&scnt[g0], 1);
            if (p0 < CAP) slist[g0][p0] = make_float2(x0, x1);
            int p1 = atomicAdd(&scnt[g0 + 1], 1);
            if (p1 < CAP) slist[g0 + 1][p1] = make_float2(x0, x1);
        }
    }
    __syncthreads();

    // Phase 2: wave w sweeps rows R+4w .. R+4w+3 in address order.
    const int wave = t >> 6;
    const int lane = t & 63;
    float* obase = out + (size_t)b * (IMH * IMW);

    for (int r = 0; r < 4; ++r) {
        const int   py  = R + wave * 4 + r;
        const float fpy = (float)py;
        float* orow = obase + (size_t)py * IMW;
        #pragma unroll
        for (int h = 0; h < 2; ++h) {             // two 256-px halves per row
            const int px0 = h * 256 + lane * 4;   // lane's 4 contiguous px
            const int s   = (h << 3) + (lane >> 3); // lane's col subtile
            const int n   = min(scnt[s], CAP);
            float acc[4] = {0.0f, 0.0f, 0.0f, 0.0f};
            for (int j = 0; j < n; ++j) {
                float2 e = slist[s][j];           // 8-lane-group broadcast
                int   i0   = (int)e.x;
                int   i1   = (int)e.y;
                float dy   = fpy - e.y;
                float dy2e = dy * dy + 1e-6f;
                bool  in1  = (unsigned)(py - i1 + HALF) <= (unsigned)(2 * HALF);
                #pragma unroll
                for (int c = 0; c < 4; ++c) {
                    int   px  = px0 + c;
                    float dx  = (float)px - e.x;
                    bool  in0 = (unsigned)(px - i0 + HALF) <= (unsigned)(2 * HALF);
                    // val = 1/(1+sqrt(d2)); hw sqrt+rcp ~1 ulp, threshold 4.3e-2
                    float v = __builtin_amdgcn_rcpf(1.0f + __builtin_amdgcn_sqrtf(dx * dx + dy2e));
                    acc[c] += (in0 && in1) ? v : 0.0f;
                }
            }
            // 64 lanes x 16 B = 1 KB contiguous per wave-store instruction.
            f32x4 v4 = { acc[0], acc[1], acc[2], acc[3] };
            *reinterpret_cast<f32x4*>(orow + px0) = v4;
        }
    }
}

extern "C" void kernel_launch(void* const* d_in, const int* in_sizes, int n_in,
                              void* d_out, int out_size, void* d_ws, size_t ws_size,
                              hipStream_t stream)
{
    // d_in[0] = img (unused by the reference); d_in[1] = landmarks [B, L, 2] f32
    const float* landmarks = (const float*)d_in[1];
    float* out = (float*)d_out;

    const int B = out_size / (IMH * IMW);   // 64
    const int L = in_sizes[1] / (2 * B);    // 106

    lm_rowsweep_kernel<<<B * NBND, 256, 0, stream>>>(landmarks, out, L);
}